// Round 1
// baseline (95.595 us; speedup 1.0000x reference)
//
#include <hip/hip_runtime.h>
#include <hip/hip_bf16.h>
#include <cstdint>
#include <cstddef>

// Problem constants: B=4, T=1024, E=512, H=64, d_k=8
#define T_DIM 1024
#define E_DIM 512

typedef short bf16x8 __attribute__((ext_vector_type(8)));
typedef float f32x4  __attribute__((ext_vector_type(4)));
typedef float f32x16 __attribute__((ext_vector_type(16)));

// ---------------------------------------------------------------------------
// Kernel A: MFMA attention, R16 = R15 with the score MFMA moved from
// 16x16x32 (25% K-util at d=8) to 32x32x16 (50% K-util).
//
// Score: one 32x32x16 MFMA covers 32 keys x 32 queries (vs four 16x16x32).
//   A = ka: half0 lanes hold key (lane&31)'s 8 d-values (k=0..7), half1
//   lanes broadcast projA[key0] (garbage, annihilated by bq zeros in
//   k=8..15).  B = bq: half0 = query d-values, half1 = zeros.
//   C = MAGIC broadcast (Schraudolph: low 16 bits of each fp32 result ARE
//   the bf16 e-value, exponent pinned at 150; uniform bias cancels in the
//   softmax normalization).
// PV (still 16-elem-N, but 32x32x16): the score output's query index is
//   lane&31 and the PV A-operand's m is ALSO lane&31 -> pack regs 0..7 into
//   PV#1's A-frag, regs 8..15 into PV#2's (8 v_perm per tile, zero
//   cross-lane traffic).  The implied k-slot->key permutation
//   key0 + (e&3) + 8*(e>>2) + 4*half (+16 for PV#2) is matched on the B
//   side by four uint2 LDS reads of projT.  projT row 8 = ones -> den free
//   in output col 8; rows 9..31 map to the zeros row -> cols 9..31 unused
//   and harmless.
// Per kc per wave: 12 MFMA (233 SIMD-cyc) -> 4 MFMA (128 SIMD-cyc); LDS
// service 2xb128+2xb64 -> 1xb128+4xb64.  MFMA floor 12.4 -> 6.9 us.
// R14/R15-verified pieces kept: magic-add score C, pack via v_perm, rcp
// epilogue (den>0 always; ~1ulp invisible in bf16), unrolled kc loop with
// all-immediate LDS offsets, ka broadcast for the annihilated half.
// ---------------------------------------------------------------------------
__global__ __launch_bounds__(1024)
void qattn_mfma(const float* __restrict__ x,
                const float* __restrict__ theta,
                const float* __restrict__ W,
                __hip_bfloat16* __restrict__ attn_out, // [4096][512] bf16
                __hip_bfloat16* __restrict__ w_bf)     // [512][512] bf16
{
    // projA (16384 B) immediately followed by projT (10 x 1032 x 2 B).
    __shared__ __align__(16) char shraw[16384 + 20640];
    auto projA = (__hip_bfloat16 (*)[8])(shraw);            // [key][d]
    auto projT = (__hip_bfloat16 (*)[1032])(shraw + 16384); // [row][key]

    const int head = blockIdx.x;        // 0..255
    const int b    = head >> 6;
    const int h    = head & 63;
    const int tid  = threadIdx.x;       // 0..1023
    const int lane = tid & 63;
    const int wv   = tid >> 6;          // 0..15
    const int l31  = lane & 31;
    const int hf   = lane >> 5;         // half: 0 or 1

    // Folded W fp32->bf16 convert: blocks 0..63 cover 512*512/4 threads.
    {
        const int gid = head * 1024 + tid;
        if (gid < 65536) {
            const float4 v = *(const float4*)(W + gid * 4);
            alignas(8) __hip_bfloat16 ob[4] = {
                __float2bfloat16(v.x), __float2bfloat16(v.y),
                __float2bfloat16(v.z), __float2bfloat16(v.w)};
            *(uint2*)(w_bf + gid * 4) = *(const uint2*)ob;
        }
    }

    // sqrt(2^7 * (1/sqrt(8)) * log2(e)) = 8.08043: score MFMA emits
    // t16 = 2^7 * x on top of the magic C.
    const float SA2 = 8.0804315f;
    float ctT[8], ctA[8];
#pragma unroll
    for (int d = 0; d < 8; ++d) {
        ctT[d] = __cosf(theta[d]);
        ctA[d] = ctT[d] * SA2;
    }

    // Stage full-head proj: 1024 rows, one per thread; plus ones/zeros rows.
    const float* xb = x + (size_t)b * T_DIM * E_DIM + h * 8;
    {
        const int r = tid;
        const float4 v0 = *(const float4*)(xb + (size_t)r * E_DIM);
        const float4 v1 = *(const float4*)(xb + (size_t)r * E_DIM + 4);
        float pr[8] = {v0.x, v0.y, v0.z, v0.w, v1.x, v1.y, v1.z, v1.w};
        alignas(16) __hip_bfloat16 ra[8];
#pragma unroll
        for (int d = 0; d < 8; ++d) {
            const float c = __cosf(pr[d]);
            ra[d] = __float2bfloat16(c * ctA[d]);
            projT[d][r] = __float2bfloat16(c * ctT[d]);
        }
        *(uint4*)&projA[r][0] = *(const uint4*)ra;
        projT[8][r] = __ushort_as_bfloat16((unsigned short)0x3f80); // ones
        projT[9][r] = __ushort_as_bfloat16((unsigned short)0);      // zeros
    }
    __syncthreads();

    const bf16x8 z8 = {};

    // Magic C: 2^23 + 2^7*126.9568, broadcast into all 16 acc regs.
    const float MAGIC = 8404858.0f;
    f32x16 cinit;
#pragma unroll
    for (int i = 0; i < 16; ++i) cinit[i] = MAGIC;

    // This wave owns 64 queries = 2 tiles of 32. bq zeroed for half1 --
    // this is what makes ka content irrelevant for k>=8.
    const int q0 = wv * 64;
    bf16x8 bq[2];
#pragma unroll
    for (int qt = 0; qt < 2; ++qt)
        bq[qt] = (hf == 0) ? *(const bf16x8*)&projA[q0 + qt * 32 + l31][0]
                           : z8;

    f32x16 nacc[2] = {};

    // Fixed bases; all per-kc offsets are compile-time immediates.
    // ka: half1 aliases half0/l31=0's row -> LDS broadcast (values garbage,
    // annihilated by bq zeros).
    const __hip_bfloat16* kabase =
        (hf == 0) ? &projA[l31][0] : &projA[0][0];
    const int bvrow = (l31 < 8) ? l31 : ((l31 == 8) ? 8 : 9);
    const __hip_bfloat16* bvbase = &projT[bvrow][hf * 4];

#pragma unroll
    for (int kc = 0; kc < 32; ++kc) {           // 32-key chunks, UNROLLED
        const int key0 = kc * 32;
        const bf16x8 ka = *(const bf16x8*)(kabase + (size_t)key0 * 8);

        // B operands for the two PV MFMAs: element e of half hf must be
        // V[key0 + (e&3) + 8*(e>>2) + 4*hf (+16)][n], matching the pack.
        union { uint2 u[2]; bf16x8 v; } bA, bB;
        bA.u[0] = *(const uint2*)(bvbase + key0);
        bA.u[1] = *(const uint2*)(bvbase + key0 + 8);
        bB.u[0] = *(const uint2*)(bvbase + key0 + 16);
        bB.u[1] = *(const uint2*)(bvbase + key0 + 24);

#pragma unroll
        for (int qt = 0; qt < 2; ++qt) {
            // Score: D[key][query] = MAGIC + 2^7*x, exponent pinned at 150.
            const f32x16 s = __builtin_amdgcn_mfma_f32_32x32x16_bf16(
                ka, bq[qt], cinit, 0, 0, 0);

            // Pack: low 16 bits of each fp32 ARE the bf16 e-value.
            // regs 0..7 -> PV#1 A-frag, regs 8..15 -> PV#2 A-frag.
            union { f32x16 f; uint32_t u[16]; } a;
            a.f = s;
            union { uint32_t u[4]; bf16x8 v; } pA, pB;
#pragma unroll
            for (int i = 0; i < 4; ++i) {
                pA.u[i] = __builtin_amdgcn_perm(a.u[2 * i + 1], a.u[2 * i],
                                                0x05040100u);
                pB.u[i] = __builtin_amdgcn_perm(a.u[8 + 2 * i + 1],
                                                a.u[8 + 2 * i], 0x05040100u);
            }
            nacc[qt] = __builtin_amdgcn_mfma_f32_32x32x16_bf16(
                pA.v, bA.v, nacc[qt], 0, 0, 0);
            nacc[qt] = __builtin_amdgcn_mfma_f32_32x32x16_bf16(
                pB.v, bB.v, nacc[qt], 0, 0, 0);
        }
    }

    // Epilogue: nacc[qt] reg r = num[q = q0+qt*32+(r&3)+8*(r>>2)+4*hf]
    // [d = l31]; col 8 = den.  v_rcp_f32 + mul instead of exact divide
    // (den > 0; bf16-invisible err).
    const int denSrc = (lane & 32) | 8;   // lane with l31==8 in same half
#pragma unroll
    for (int qt = 0; qt < 2; ++qt) {
#pragma unroll
        for (int r = 0; r < 16; ++r) {
            const float den = __shfl(nacc[qt][r], denSrc);
            const float inv = __builtin_amdgcn_rcpf(den);
            if (l31 < 8) {
                const int qrow = q0 + qt * 32 + (r & 3) + 8 * (r >> 2) + 4 * hf;
                attn_out[(size_t)(b * T_DIM + qrow) * E_DIM + h * 8 + l31] =
                    __float2bfloat16(nacc[qt][r] * inv);
            }
        }
    }
}

// ---------------------------------------------------------------------------
// Kernel B: out[4096][512] = attn_bf16 @ W_bf16^T + bias (fp32 out).
// R6's verified version, unchanged: 128x64 tile, BK=64, grid 32x8, XOR-
// swizzled k-chunks (slot kc^(row&7)) for conflict-free b128 frag reads.
// ---------------------------------------------------------------------------
#define BM 128
#define BN 64
#define BK 64

__global__ __launch_bounds__(256, 2)
void combine_gemm(const __hip_bfloat16* __restrict__ A,  // [4096][512]
                  const __hip_bfloat16* __restrict__ Wb, // [512][512] (N,K)
                  const float* __restrict__ bias,        // [512]
                  float* __restrict__ out)               // [4096][512]
{
    __shared__ __hip_bfloat16 As[BM][BK];  // 16 KB
    __shared__ __hip_bfloat16 Bs[BN][BK];  // 8 KB

    const int tid  = threadIdx.x;
    const int lane = tid & 63;
    const int wave = tid >> 6;
    const int bm   = blockIdx.x;          // 0..31
    const int bn   = blockIdx.y;          // 0..7
    const int wm   = (wave & 1) * 64;
    const int wn   = (wave >> 1) * 32;
    const int rlo  = lane & 15;
    const int quad = lane >> 4;

    f32x4 acc[4][2] = {};

    for (int k0 = 0; k0 < E_DIM; k0 += BK) {
        if (k0) __syncthreads();
        // A: 128 rows x 8 chunks(16B) = 1024 chunks, 4 passes of 256.
#pragma unroll
        for (int p = 0; p < 4; ++p) {
            const int c   = p * 256 + tid;
            const int row = c >> 3;
            const int kcs = c & 7;                 // LDS slot
            const int kc  = kcs ^ (row & 7);       // global chunk (swizzle)
            const __hip_bfloat16* gA =
                A + (size_t)(bm * BM + row) * E_DIM + k0 + kc * 8;
            char* lA = (char*)As + (size_t)(p * 256 + wave * 64) * 16;
            __builtin_amdgcn_global_load_lds(
                (const __attribute__((address_space(1))) void*)gA,
                (__attribute__((address_space(3))) void*)lA, 16, 0, 0);
        }
        // B: 64 rows x 8 chunks = 512 chunks, 2 passes of 256.
#pragma unroll
        for (int p = 0; p < 2; ++p) {
            const int c   = p * 256 + tid;
            const int row = c >> 3;
            const int kcs = c & 7;
            const int kc  = kcs ^ (row & 7);
            const __hip_bfloat16* gW =
                Wb + (size_t)(bn * BN + row) * E_DIM + k0 + kc * 8;
            char* lB = (char*)Bs + (size_t)(p * 256 + wave * 64) * 16;
            __builtin_amdgcn_global_load_lds(
                (const __attribute__((address_space(1))) void*)gW,
                (__attribute__((address_space(3))) void*)lB, 16, 0, 0);
        }
        __syncthreads();

#pragma unroll
        for (int ks = 0; ks < 2; ++ks) {
            const int kci  = ks * 4 + quad;              // wanted k-chunk
            const int koff = (kci ^ (rlo & 7)) * 8;      // swizzled LDS off
            bf16x8 af[4], bf[2];
#pragma unroll
            for (int i = 0; i < 4; ++i)
                af[i] = *(const bf16x8*)&As[wm + i * 16 + rlo][koff];
#pragma unroll
            for (int j = 0; j < 2; ++j)
                bf[j] = *(const bf16x8*)&Bs[wn + j * 16 + rlo][koff];
#pragma unroll
            for (int i = 0; i < 4; ++i)
#pragma unroll
                for (int j = 0; j < 2; ++j)
                    acc[i][j] = __builtin_amdgcn_mfma_f32_16x16x32_bf16(
                        af[i], bf[j], acc[i][j], 0, 0, 0);
        }
    }

    // Epilogue: C/D layout col = lane&15, row = quad*4 + reg.
    const int row0 = bm * BM + wm;
    const int col0 = bn * BN + wn;
#pragma unroll
    for (int j = 0; j < 2; ++j) {
        const int col = col0 + j * 16 + rlo;
        const float bv = bias[col];
#pragma unroll
        for (int i = 0; i < 4; ++i) {
            const int rbase = row0 + i * 16 + quad * 4;
#pragma unroll
            for (int r = 0; r < 4; ++r)
                out[(size_t)(rbase + r) * E_DIM + col] = acc[i][j][r] + bv;
        }
    }
}

// ---------------------------------------------------------------------------
extern "C" void kernel_launch(void* const* d_in, const int* in_sizes, int n_in,
                              void* d_out, int out_size, void* d_ws,
                              size_t ws_size, hipStream_t stream)
{
    const float* x     = (const float*)d_in[0];  // [4,1024,512]
    const float* theta = (const float*)d_in[1];  // [8]
    const float* W     = (const float*)d_in[2];  // [512,512]
    const float* bias  = (const float*)d_in[3];  // [512]
    float* out = (float*)d_out;                  // [4,1024,512] fp32

    // ws layout: attn_bf16 [4096*512] = 4 MB, then W_bf16 [512*512] = 512 KB
    __hip_bfloat16* attn_bf = (__hip_bfloat16*)d_ws;
    __hip_bfloat16* w_bf    = (__hip_bfloat16*)((char*)d_ws + 4u * 1024u * 1024u);

    hipLaunchKernelGGL(qattn_mfma, dim3(256), dim3(1024), 0, stream,
                       x, theta, W, attn_bf, w_bf);
    hipLaunchKernelGGL(combine_gemm, dim3(32, 8), dim3(256), 0, stream,
                       attn_bf, w_bf, bias, out);
}

// Round 2
// 92.048 us; speedup vs baseline: 1.0385x; 1.0385x over previous
//
#include <hip/hip_runtime.h>
#include <hip/hip_bf16.h>
#include <cstdint>
#include <cstddef>

// Problem constants: B=4, T=1024, E=512, H=64, d_k=8
#define T_DIM 1024
#define E_DIM 512

typedef short bf16x8 __attribute__((ext_vector_type(8)));
typedef float f32x4  __attribute__((ext_vector_type(4)));
typedef float f32x16 __attribute__((ext_vector_type(16)));

// ---------------------------------------------------------------------------
// Kernel A: MFMA attention. R17 = R16 core (32x32x16 score+PV, verified
// absmax 0.0098) with an OCCUPANCY restructure: 512 blocks x 512 threads
// (2 blocks/CU, each block = half of one head's queries) instead of
// 256 x 1024 (1 block/CU). R16 proved the kernel is not MFMA-bound
// (halving MFMA work was time-neutral), so the cost is exposed latency:
// with one barrier domain per CU, the staging global-loads + cos prologue
// and the shfl/store epilogue serialize against the MFMA loop. Two
// independent blocks per CU let one block's prologue/epilogue hide under
// the other's compute. Staging is duplicated per half (x re-read, cos x2)
// -- ~1.3 us aggregate, a good trade if latency exposure is the real cost.
// Block swizzle pairs the two halves of a head on the SAME XCD (p and p+8
// land on one XCD under round-robin dispatch) so the duplicated x-slice
// fetch hits L2.
//
// Verified core kept bit-identical: magic-add Schraudolph score C
// (low 16 bits of fp32 result ARE the bf16 e-value, exponent pinned 150;
// uniform bias cancels in softmax), 32x32x16 score with half1 bq zeros
// annihilating broadcast ka garbage, pi-trick pack (regs 0..7 -> PV#1
// A-frag, 8..15 -> PV#2; k-permutation matched by 4 uint2 projT reads),
// projT row 8 = ones -> den in col 8, rcp epilogue.
// ---------------------------------------------------------------------------
__global__ __launch_bounds__(512, 4)
void qattn_mfma(const float* __restrict__ x,
                const float* __restrict__ theta,
                const float* __restrict__ W,
                __hip_bfloat16* __restrict__ attn_out, // [4096][512] bf16
                __hip_bfloat16* __restrict__ w_bf)     // [512][512] bf16
{
    // projA (16384 B) immediately followed by projT (10 x 1032 x 2 B).
    __shared__ __align__(16) char shraw[16384 + 20640];
    auto projA = (__hip_bfloat16 (*)[8])(shraw);            // [key][d]
    auto projT = (__hip_bfloat16 (*)[1032])(shraw + 16384); // [row][key]

    // XCD-pairing swizzle: round-robin dispatch puts p and p+8 on the same
    // XCD; make them the two query-halves of one head (bijective).
    const int p    = blockIdx.x;        // 0..511
    const int xcd  = p & 7;
    const int idx  = p >> 3;            // 0..63 within XCD
    const int head = xcd * 32 + (idx >> 1);   // 0..255
    const int qh   = idx & 1;           // query half
    const int b    = head >> 6;
    const int h    = head & 63;
    const int tid  = threadIdx.x;       // 0..511
    const int lane = tid & 63;
    const int wv   = tid >> 6;          // 0..7
    const int l31  = lane & 31;
    const int hf   = lane >> 5;         // half: 0 or 1

    // Folded W fp32->bf16 convert: 65536 float4s over the first 128 blocks.
    {
        const int gid = p * 512 + tid;
        if (gid < 65536) {
            const float4 v = *(const float4*)(W + gid * 4);
            alignas(8) __hip_bfloat16 ob[4] = {
                __float2bfloat16(v.x), __float2bfloat16(v.y),
                __float2bfloat16(v.z), __float2bfloat16(v.w)};
            *(uint2*)(w_bf + gid * 4) = *(const uint2*)ob;
        }
    }

    // sqrt(2^7 * (1/sqrt(8)) * log2(e)) = 8.08043: score MFMA emits
    // t16 = 2^7 * x on top of the magic C.
    const float SA2 = 8.0804315f;
    float ctT[8], ctA[8];
#pragma unroll
    for (int d = 0; d < 8; ++d) {
        ctT[d] = __cosf(theta[d]);
        ctA[d] = ctT[d] * SA2;
    }

    // Stage full-head proj: 1024 rows, TWO per thread; plus ones/zeros rows.
    const float* xb = x + (size_t)b * T_DIM * E_DIM + h * 8;
#pragma unroll
    for (int rr = 0; rr < 2; ++rr) {
        const int r = tid + rr * 512;
        const float4 v0 = *(const float4*)(xb + (size_t)r * E_DIM);
        const float4 v1 = *(const float4*)(xb + (size_t)r * E_DIM + 4);
        float pr[8] = {v0.x, v0.y, v0.z, v0.w, v1.x, v1.y, v1.z, v1.w};
        alignas(16) __hip_bfloat16 ra[8];
#pragma unroll
        for (int d = 0; d < 8; ++d) {
            const float c = __cosf(pr[d]);
            ra[d] = __float2bfloat16(c * ctA[d]);
            projT[d][r] = __float2bfloat16(c * ctT[d]);
        }
        *(uint4*)&projA[r][0] = *(const uint4*)ra;
        projT[8][r] = __ushort_as_bfloat16((unsigned short)0x3f80); // ones
        projT[9][r] = __ushort_as_bfloat16((unsigned short)0);      // zeros
    }
    __syncthreads();

    const bf16x8 z8 = {};

    // Magic C: 2^23 + 2^7*126.9568, broadcast into all 16 acc regs.
    const float MAGIC = 8404858.0f;
    f32x16 cinit;
#pragma unroll
    for (int i = 0; i < 16; ++i) cinit[i] = MAGIC;

    // This wave owns 64 queries = 2 tiles of 32, in this block's half.
    // bq zeroed for half1 -- makes ka content irrelevant for k>=8.
    const int q0 = qh * 512 + wv * 64;
    bf16x8 bq[2];
#pragma unroll
    for (int qt = 0; qt < 2; ++qt)
        bq[qt] = (hf == 0) ? *(const bf16x8*)&projA[q0 + qt * 32 + l31][0]
                           : z8;

    f32x16 nacc[2] = {};

    // Fixed bases; all per-kc offsets are compile-time immediates.
    // ka: half1 aliases row 0 -> LDS broadcast (values garbage, annihilated
    // by bq zeros).
    const __hip_bfloat16* kabase =
        (hf == 0) ? &projA[l31][0] : &projA[0][0];
    const int bvrow = (l31 < 8) ? l31 : ((l31 == 8) ? 8 : 9);
    const __hip_bfloat16* bvbase = &projT[bvrow][hf * 4];

#pragma unroll
    for (int kc = 0; kc < 32; ++kc) {           // 32-key chunks, UNROLLED
        const int key0 = kc * 32;
        const bf16x8 ka = *(const bf16x8*)(kabase + (size_t)key0 * 8);

        // B operands for the two PV MFMAs: element e of half hf must be
        // V[key0 + (e&3) + 8*(e>>2) + 4*hf (+16)][n], matching the pack.
        union { uint2 u[2]; bf16x8 v; } bA, bB;
        bA.u[0] = *(const uint2*)(bvbase + key0);
        bA.u[1] = *(const uint2*)(bvbase + key0 + 8);
        bB.u[0] = *(const uint2*)(bvbase + key0 + 16);
        bB.u[1] = *(const uint2*)(bvbase + key0 + 24);

#pragma unroll
        for (int qt = 0; qt < 2; ++qt) {
            // Score: D[key][query] = MAGIC + 2^7*x, exponent pinned at 150.
            const f32x16 s = __builtin_amdgcn_mfma_f32_32x32x16_bf16(
                ka, bq[qt], cinit, 0, 0, 0);

            // Pack: low 16 bits of each fp32 ARE the bf16 e-value.
            // regs 0..7 -> PV#1 A-frag, regs 8..15 -> PV#2 A-frag.
            union { f32x16 f; uint32_t u[16]; } a;
            a.f = s;
            union { uint32_t u[4]; bf16x8 v; } pA, pB;
#pragma unroll
            for (int i = 0; i < 4; ++i) {
                pA.u[i] = __builtin_amdgcn_perm(a.u[2 * i + 1], a.u[2 * i],
                                                0x05040100u);
                pB.u[i] = __builtin_amdgcn_perm(a.u[8 + 2 * i + 1],
                                                a.u[8 + 2 * i], 0x05040100u);
            }
            nacc[qt] = __builtin_amdgcn_mfma_f32_32x32x16_bf16(
                pA.v, bA.v, nacc[qt], 0, 0, 0);
            nacc[qt] = __builtin_amdgcn_mfma_f32_32x32x16_bf16(
                pB.v, bB.v, nacc[qt], 0, 0, 0);
        }
    }

    // Epilogue: nacc[qt] reg r = num[q = q0+qt*32+(r&3)+8*(r>>2)+4*hf]
    // [d = l31]; col 8 = den.  v_rcp_f32 + mul instead of exact divide
    // (den > 0; bf16-invisible err).
    const int denSrc = (lane & 32) | 8;   // lane with l31==8 in same half
#pragma unroll
    for (int qt = 0; qt < 2; ++qt) {
#pragma unroll
        for (int r = 0; r < 16; ++r) {
            const float den = __shfl(nacc[qt][r], denSrc);
            const float inv = __builtin_amdgcn_rcpf(den);
            if (l31 < 8) {
                const int qrow = q0 + qt * 32 + (r & 3) + 8 * (r >> 2) + 4 * hf;
                attn_out[(size_t)(b * T_DIM + qrow) * E_DIM + h * 8 + l31] =
                    __float2bfloat16(nacc[qt][r] * inv);
            }
        }
    }
}

// ---------------------------------------------------------------------------
// Kernel B: out[4096][512] = attn_bf16 @ W_bf16^T + bias (fp32 out).
// R17: BM 128 -> 64, grid (64,8) = 512 blocks -> 2 blocks/CU (was 1 block/CU
// = 1 wave/SIMD: every vmcnt(0)+barrier drain of the 8 k-iters was fully
// exposed with no co-resident wave). Same verified XOR-swizzled k-chunk
// scheme (slot kc^(row&7)) for conflict-free b128 frag reads; same
// K-accumulation order -> bit-identical output.
// ---------------------------------------------------------------------------
#define BM 64
#define BN 64
#define BK 64

__global__ __launch_bounds__(256, 2)
void combine_gemm(const __hip_bfloat16* __restrict__ A,  // [4096][512]
                  const __hip_bfloat16* __restrict__ Wb, // [512][512] (N,K)
                  const float* __restrict__ bias,        // [512]
                  float* __restrict__ out)               // [4096][512]
{
    __shared__ __hip_bfloat16 As[BM][BK];  // 8 KB
    __shared__ __hip_bfloat16 Bs[BN][BK];  // 8 KB

    const int tid  = threadIdx.x;
    const int lane = tid & 63;
    const int wave = tid >> 6;
    const int bm   = blockIdx.x;          // 0..63
    const int bn   = blockIdx.y;          // 0..7
    const int wm   = (wave & 1) * 32;
    const int wn   = (wave >> 1) * 32;
    const int rlo  = lane & 15;
    const int quad = lane >> 4;

    f32x4 acc[2][2] = {};

    for (int k0 = 0; k0 < E_DIM; k0 += BK) {
        if (k0) __syncthreads();
        // A: 64 rows x 8 chunks(16B) = 512 chunks, 2 passes of 256.
#pragma unroll
        for (int pp = 0; pp < 2; ++pp) {
            const int c   = pp * 256 + tid;
            const int row = c >> 3;
            const int kcs = c & 7;                 // LDS slot
            const int kc  = kcs ^ (row & 7);       // global chunk (swizzle)
            const __hip_bfloat16* gA =
                A + (size_t)(bm * BM + row) * E_DIM + k0 + kc * 8;
            char* lA = (char*)As + (size_t)(pp * 256 + wave * 64) * 16;
            __builtin_amdgcn_global_load_lds(
                (const __attribute__((address_space(1))) void*)gA,
                (__attribute__((address_space(3))) void*)lA, 16, 0, 0);
        }
        // B: 64 rows x 8 chunks = 512 chunks, 2 passes of 256.
#pragma unroll
        for (int pp = 0; pp < 2; ++pp) {
            const int c   = pp * 256 + tid;
            const int row = c >> 3;
            const int kcs = c & 7;
            const int kc  = kcs ^ (row & 7);
            const __hip_bfloat16* gW =
                Wb + (size_t)(bn * BN + row) * E_DIM + k0 + kc * 8;
            char* lB = (char*)Bs + (size_t)(pp * 256 + wave * 64) * 16;
            __builtin_amdgcn_global_load_lds(
                (const __attribute__((address_space(1))) void*)gW,
                (__attribute__((address_space(3))) void*)lB, 16, 0, 0);
        }
        __syncthreads();

#pragma unroll
        for (int ks = 0; ks < 2; ++ks) {
            const int kci  = ks * 4 + quad;              // wanted k-chunk
            const int koff = (kci ^ (rlo & 7)) * 8;      // swizzled LDS off
            bf16x8 af[2], bf[2];
#pragma unroll
            for (int i = 0; i < 2; ++i)
                af[i] = *(const bf16x8*)&As[wm + i * 16 + rlo][koff];
#pragma unroll
            for (int j = 0; j < 2; ++j)
                bf[j] = *(const bf16x8*)&Bs[wn + j * 16 + rlo][koff];
#pragma unroll
            for (int i = 0; i < 2; ++i)
#pragma unroll
                for (int j = 0; j < 2; ++j)
                    acc[i][j] = __builtin_amdgcn_mfma_f32_16x16x32_bf16(
                        af[i], bf[j], acc[i][j], 0, 0, 0);
        }
    }

    // Epilogue: C/D layout col = lane&15, row = quad*4 + reg.
    const int row0 = bm * BM + wm;
    const int col0 = bn * BN + wn;
#pragma unroll
    for (int j = 0; j < 2; ++j) {
        const int col = col0 + j * 16 + rlo;
        const float bv = bias[col];
#pragma unroll
        for (int i = 0; i < 2; ++i) {
            const int rbase = row0 + i * 16 + quad * 4;
#pragma unroll
            for (int r = 0; r < 4; ++r)
                out[(size_t)(rbase + r) * E_DIM + col] = acc[i][j][r] + bv;
        }
    }
}

// ---------------------------------------------------------------------------
extern "C" void kernel_launch(void* const* d_in, const int* in_sizes, int n_in,
                              void* d_out, int out_size, void* d_ws,
                              size_t ws_size, hipStream_t stream)
{
    const float* x     = (const float*)d_in[0];  // [4,1024,512]
    const float* theta = (const float*)d_in[1];  // [8]
    const float* W     = (const float*)d_in[2];  // [512,512]
    const float* bias  = (const float*)d_in[3];  // [512]
    float* out = (float*)d_out;                  // [4,1024,512] fp32

    // ws layout: attn_bf16 [4096*512] = 4 MB, then W_bf16 [512*512] = 512 KB
    __hip_bfloat16* attn_bf = (__hip_bfloat16*)d_ws;
    __hip_bfloat16* w_bf    = (__hip_bfloat16*)((char*)d_ws + 4u * 1024u * 1024u);

    hipLaunchKernelGGL(qattn_mfma, dim3(512), dim3(512), 0, stream,
                       x, theta, W, attn_bf, w_bf);
    hipLaunchKernelGGL(combine_gemm, dim3(64, 8), dim3(256), 0, stream,
                       attn_bf, w_bf, bias, out);
}